// Round 11
// baseline (2142.595 us; speedup 1.0000x reference)
//
#include <hip/hip_runtime.h>

#define B_DIM 16
#define L_DIM 1024
#define D_DIM 512
#define H_DIM 256
#define K_DIM 4

#define SLICES 8        // scan wgs per batch
#define RPW 32          // rows per scan wg
#define MAGIC 0x5EEDBEEFu

// ---------------- workspace layout (bytes) ----------------
#define OFF_HB    0                    // u64 hb[2][16][256] (tag<<32 | f32), 64KB
#define OFF_FLAGN 65536                // u32 flag_n[16*64] (rN/SEL chunk ready)
#define OFF_SEL   131072               // float SEL[16384*4] (256KB)
#define OFF_RN    393216               // float rN[16384*256] (16MB)

__device__ __forceinline__ float fast_log2(float x) { return __builtin_amdgcn_logf(x); }
__device__ __forceinline__ float fast_exp2(float x) { return __builtin_amdgcn_exp2f(x); }

// ---------------- single fused kernel ----------------
// blocks [0,128): scan role   (U-prologue for its private 32-col stripe,
//                              hb self-init, then R9-structure scan)
// blocks [128,1152): norm role (inline selector+softmax -> SEL, Lp norms -> rN,
//                              then per-chunk ready flag)
// All cross-role data (SEL, rN) is value-idempotent across replays, so stale
// MAGIC flags from a previous replay are benign (reader gets identical values).
// out is private to each scan wg (prologue writes U stripe, scan RMWs it).
// hb is self-tagged and zeroed by its owner wgs before any publish (skew<=1
// argument makes zero-vs-publish races impossible).
__global__ __launch_bounds__(256) void k_all(const float* __restrict__ x,
                                             const float* __restrict__ Wsel,
                                             const float* __restrict__ bsel,
                                             const float* __restrict__ W_B,
                                             const float* __restrict__ M,
                                             float* __restrict__ SEL,
                                             float* __restrict__ rN,
                                             float* __restrict__ out,
                                             unsigned long long* __restrict__ hb,
                                             unsigned int* __restrict__ flag_n) {
    __shared__ float g_lds[256];
    __shared__ float part_lds[256];
    __shared__ float4 sel_lds[16];
    const int bid = blockIdx.x;
    const int tid = threadIdx.x;

    if (bid < 128) {
        // ================= scan role =================
        __builtin_amdgcn_s_setprio(1);
        const int wg = bid;
        const int b = wg & 15;
        const int slice = wg >> 4;

        // ---- prologue: U stripe (b, cols slice*32..+32, all t) into out ----
        {
            const int c = tid & 31;
            const int tg = tid >> 5;
            const int cg = slice * 32 + c;
            const float4* wrow = (const float4*)(W_B + (size_t)cg * D_DIM);
            const float* xb = x + (size_t)b * L_DIM * D_DIM;
            for (int tb = 0; tb < 16; ++tb) {
                float acc[8] = {};
                for (int dc = 0; dc < 8; ++dc) {
                    float4 wv[16];
#pragma unroll
                    for (int u = 0; u < 16; ++u) wv[u] = wrow[dc * 16 + u];
#pragma unroll
                    for (int tt = 0; tt < 8; ++tt) {
                        const int t = tb * 64 + tg * 8 + tt;
                        const float4* xr = (const float4*)(xb + (size_t)t * D_DIM) + dc * 16;
                        float a = 0.0f;
#pragma unroll
                        for (int u = 0; u < 16; ++u) {
                            float4 xv = xr[u];
                            a = fmaf(wv[u].x, xv.x, a);
                            a = fmaf(wv[u].y, xv.y, a);
                            a = fmaf(wv[u].z, xv.z, a);
                            a = fmaf(wv[u].w, xv.w, a);
                        }
                        acc[tt] += a;
                    }
                }
#pragma unroll
                for (int tt = 0; tt < 8; ++tt) {
                    const int t = tb * 64 + tg * 8 + tt;
                    out[(size_t)(b * L_DIM + t) * H_DIM + cg] = acc[tt];
                }
            }
        }

        // ---- hb self-init: zero own rows, both parities ----
        if (tid < RPW) {
            __hip_atomic_store(hb + 4096 + b * 256 + slice * RPW + tid, 0ull,
                               __ATOMIC_RELAXED, __HIP_MEMORY_SCOPE_AGENT);
            __hip_atomic_store(hb + b * 256 + slice * RPW + tid, 0ull,
                               __ATOMIC_RELAXED, __HIP_MEMORY_SCOPE_AGENT);
        }
        __threadfence();     // own U stores + hb zeros agent-visible
        __syncthreads();     // whole wg done before any detect/uval read

        // ---- load M slice into registers (R9 mapping) ----
        const int q = tid >> 6;
        const int ti = tid & 63;
        const int r = ti & 31;
        const int js = ti >> 5;
        const int ig = slice * RPW + r;
        const int jbase = q * 64 + js * 32;
        float m[128];
        {
            const float4* M4 = (const float4*)M;
#pragma unroll
            for (int jj = 0; jj < 32; ++jj) {
                float4 v = M4[ig * H_DIM + jbase + jj];
                m[jj * 4 + 0] = v.x; m[jj * 4 + 1] = v.y;
                m[jj * 4 + 2] = v.z; m[jj * 4 + 3] = v.w;
            }
        }

        // ---- R9-structure scan loop + chunk-flag gating ----
#pragma unroll 1
        for (int t = 0; t < L_DIM; ++t) {
            if ((t & 15) == 0) {
                const unsigned int* fl = flag_n + b * 64 + (t >> 4);
                while (__hip_atomic_load(fl, __ATOMIC_ACQUIRE, __HIP_MEMORY_SCOPE_AGENT)
                       != MAGIC)
                    __builtin_amdgcn_s_sleep(1);
            }
            // independent loads issued before the hb poll
            float rn = rN[(size_t)(b * L_DIM + t) * H_DIM + tid];
            float4 s4 = ((const float4*)SEL)[b * L_DIM + t];
            float uval = 0.0f;
            if (tid < RPW) uval = out[(size_t)(b * L_DIM + t) * H_DIM + slice * RPW + tid];

            unsigned long long* src = hb + (size_t)(t & 1) * (16 * 256) + b * 256 + tid;
            unsigned long long w;
            while (((w = __hip_atomic_load(src, __ATOMIC_RELAXED, __HIP_MEMORY_SCOPE_AGENT)) >> 32)
                   != (unsigned int)t) { }
            float h = __uint_as_float((unsigned int)w);
            g_lds[tid] = h * rn;
            __syncthreads();

            float acc0 = 0, acc1 = 0, acc2 = 0, acc3 = 0;
            const float4* g4 = (const float4*)(g_lds + jbase);
#pragma unroll
            for (int jj4 = 0; jj4 < 8; ++jj4) {
                float4 gv = g4[jj4];
                acc0 = fmaf(m[(jj4 * 4 + 0) * 4 + 0], gv.x, acc0);
                acc1 = fmaf(m[(jj4 * 4 + 0) * 4 + 1], gv.x, acc1);
                acc2 = fmaf(m[(jj4 * 4 + 0) * 4 + 2], gv.x, acc2);
                acc3 = fmaf(m[(jj4 * 4 + 0) * 4 + 3], gv.x, acc3);
                acc0 = fmaf(m[(jj4 * 4 + 1) * 4 + 0], gv.y, acc0);
                acc1 = fmaf(m[(jj4 * 4 + 1) * 4 + 1], gv.y, acc1);
                acc2 = fmaf(m[(jj4 * 4 + 1) * 4 + 2], gv.y, acc2);
                acc3 = fmaf(m[(jj4 * 4 + 1) * 4 + 3], gv.y, acc3);
                acc0 = fmaf(m[(jj4 * 4 + 2) * 4 + 0], gv.z, acc0);
                acc1 = fmaf(m[(jj4 * 4 + 2) * 4 + 1], gv.z, acc1);
                acc2 = fmaf(m[(jj4 * 4 + 2) * 4 + 2], gv.z, acc2);
                acc3 = fmaf(m[(jj4 * 4 + 2) * 4 + 3], gv.z, acc3);
                acc0 = fmaf(m[(jj4 * 4 + 3) * 4 + 0], gv.w, acc0);
                acc1 = fmaf(m[(jj4 * 4 + 3) * 4 + 1], gv.w, acc1);
                acc2 = fmaf(m[(jj4 * 4 + 3) * 4 + 2], gv.w, acc2);
                acc3 = fmaf(m[(jj4 * 4 + 3) * 4 + 3], gv.w, acc3);
            }
            float part = fmaf(acc0, s4.x, fmaf(acc1, s4.y, fmaf(acc2, s4.z, acc3 * s4.w)));
            part_lds[tid] = part;
            __syncthreads();

            if (tid < RPW) {
                float hn = uval;
#pragma unroll
                for (int p = 0; p < 8; ++p) hn += part_lds[tid + 32 * p];
                unsigned long long pw = ((unsigned long long)(unsigned int)(t + 1) << 32) |
                                        (unsigned long long)__float_as_uint(hn);
                __hip_atomic_store(hb + (size_t)((t + 1) & 1) * (16 * 256) + b * 256 + slice * RPW + tid,
                                   pw, __ATOMIC_RELAXED, __HIP_MEMORY_SCOPE_AGENT);
                out[(size_t)(b * L_DIM + t) * H_DIM + slice * RPW + tid] = hn;
            }
        }
    } else {
        // ================= norm role =================
        const int nb = bid - 128;
        const int b = nb >> 6;
        const int t0 = (nb & 63) << 4;
        const int lane = tid & 63;
        const int wv = tid >> 6;
        const float4* w4 = (const float4*)Wsel;
#pragma unroll
        for (int rr = 0; rr < 4; ++rr) {
            const int tt = wv * 4 + rr;
            const int row = b * L_DIM + t0 + tt;
            const float4* x4 = (const float4*)(x + (size_t)row * D_DIM);
            float4 xa = x4[lane * 2], xb2 = x4[lane * 2 + 1];
            float acc[4];
#pragma unroll
            for (int k = 0; k < 4; ++k) {
                float4 wa = w4[k * (D_DIM / 4) + lane * 2];
                float4 wb = w4[k * (D_DIM / 4) + lane * 2 + 1];
                acc[k] = xa.x * wa.x + xa.y * wa.y + xa.z * wa.z + xa.w * wa.w +
                         xb2.x * wb.x + xb2.y * wb.y + xb2.z * wb.z + xb2.w * wb.w;
            }
#pragma unroll
            for (int off = 1; off < 64; off <<= 1) {
#pragma unroll
                for (int k = 0; k < 4; ++k) acc[k] += __shfl_xor(acc[k], off, 64);
            }
            if (lane == 0) {
                float z[4], mx = -1e30f;
#pragma unroll
                for (int k = 0; k < 4; ++k) { z[k] = acc[k] + bsel[k]; mx = fmaxf(mx, z[k]); }
                float e[4], s = 0.0f;
#pragma unroll
                for (int k = 0; k < 4; ++k) { e[k] = fast_exp2((z[k] - mx) * 1.4426950408889634f); s += e[k]; }
                float inv = 1.0f / s;
                float4 o = { e[0] * inv, e[1] * inv, e[2] * inv, e[3] * inv };
                sel_lds[tt] = o;
                ((float4*)SEL)[row] = o;
            }
        }
        __syncthreads();

        const int j = tid;
        float s[16][4];
#pragma unroll
        for (int tt = 0; tt < 16; ++tt) {
            float4 sv = sel_lds[tt];
            s[tt][0] = sv.x; s[tt][1] = sv.y; s[tt][2] = sv.z; s[tt][3] = sv.w;
        }
        float acc[16] = {};
        const float4* M4 = (const float4*)M;
        for (int i = 0; i < H_DIM; ++i) {
            float4 mm = M4[i * H_DIM + j];
#pragma unroll
            for (int tt = 0; tt < 16; ++tt) {
                float a = fmaf(mm.x, s[tt][0], fmaf(mm.y, s[tt][1],
                          fmaf(mm.z, s[tt][2], mm.w * s[tt][3])));
                a = fabsf(a);
                acc[tt] += fast_exp2(1.2f * fast_log2(a));  // |a|^1.2
            }
        }
#pragma unroll
        for (int tt = 0; tt < 16; ++tt) {
            rN[(size_t)(b * L_DIM + t0 + tt) * H_DIM + j] =
                fast_exp2(-0.8333333333f * fast_log2(acc[tt]));
        }

        // publish chunk-ready flag: all threads' stores visible, then MAGIC
        __threadfence();
        __syncthreads();
        if (tid == 0)
            __hip_atomic_store(flag_n + b * 64 + (t0 >> 4), MAGIC,
                               __ATOMIC_RELEASE, __HIP_MEMORY_SCOPE_AGENT);
    }
}

extern "C" void kernel_launch(void* const* d_in, const int* in_sizes, int n_in,
                              void* d_out, int out_size, void* d_ws, size_t ws_size,
                              hipStream_t stream) {
    const float* x    = (const float*)d_in[0];  // (16,1024,512)
    const float* Wsel = (const float*)d_in[1];  // (4,512)
    const float* bsel = (const float*)d_in[2];  // (4,)
    const float* W_B  = (const float*)d_in[3];  // (256,512)
    const float* M    = (const float*)d_in[4];  // (256,256,4)
    float* out = (float*)d_out;                 // (16,1024,256)

    char* ws = (char*)d_ws;
    unsigned long long* hb = (unsigned long long*)(ws + OFF_HB);
    unsigned int* flag_n   = (unsigned int*)(ws + OFF_FLAGN);
    float* SEL = (float*)(ws + OFF_SEL);
    float* rN  = (float*)(ws + OFF_RN);

    k_all<<<128 + 1024, 256, 0, stream>>>(x, Wsel, bsel, W_B, M, SEL, rN, out, hb, flag_n);
}

// Round 12
// 1317.924 us; speedup vs baseline: 1.6257x; 1.6257x over previous
//
#include <hip/hip_runtime.h>

#define B_DIM 16
#define L_DIM 1024
#define D_DIM 512
#define H_DIM 256
#define K_DIM 4

#define SLICES 8        // wgs per batch
#define RPW 32          // rows per wg (H_DIM / SLICES)

// ---------------- workspace layout (bytes) ----------------
#define OFF_HB  0                      // u64 hb [2][16][256] LLC-domain (64KB)
#define OFF_HBL 65536                  // u64 hbL[2][16][256] L2-domain  (64KB)
#define OFF_SEL 131072                 // float SEL[16384*4] (256KB)
#define OFF_RN  393216                 // float rN[16384*256] (16MB)

__device__ __forceinline__ float fast_log2(float x) { return __builtin_amdgcn_logf(x); }
__device__ __forceinline__ float fast_exp2(float x) { return __builtin_amdgcn_exp2f(x); }

// L2-domain access: sc0 = bypass L1, served by (shared, same-XCD) L2.
__device__ __forceinline__ unsigned long long ld_l2(const unsigned long long* p) {
    unsigned long long r;
    asm volatile("global_load_dwordx2 %0, %1, off sc0\n\t"
                 "s_waitcnt vmcnt(0)"
                 : "=&v"(r) : "v"(p) : "memory");
    return r;
}
__device__ __forceinline__ void st_l2(unsigned long long* p, unsigned long long v) {
    asm volatile("global_store_dwordx2 %0, %1, off sc0"
                 :: "v"(p), "v"(v) : "memory");
}

// ---------------- fused parallel phase (R9 structure, no init role) ----------------
#define GBM 64
#define GBN 64
#define GBK 32
__global__ __launch_bounds__(256) void k_par(const float* __restrict__ x,
                                             const float* __restrict__ Wsel,
                                             const float* __restrict__ bsel,
                                             const float* __restrict__ W_B,
                                             const float* __restrict__ M,
                                             float* __restrict__ SEL,
                                             float* __restrict__ rN,
                                             float* __restrict__ out) {
    __shared__ float Xs[GBK][GBM + 1];
    __shared__ float Ws[GBK][GBN + 1];
    __shared__ float4 sel_lds[16];
    const int bid = blockIdx.x;
    const int tid = threadIdx.x;

    if (bid < 1024) {
        // ---------- norm role ----------
        const int b = bid >> 6;
        const int t0 = (bid & 63) << 4;
        const int lane = tid & 63;
        const int wv = tid >> 6;
        const float4* w4 = (const float4*)Wsel;
#pragma unroll
        for (int rr = 0; rr < 4; ++rr) {
            const int tt = wv * 4 + rr;
            const int row = b * L_DIM + t0 + tt;
            const float4* x4 = (const float4*)(x + (size_t)row * D_DIM);
            float4 xa = x4[lane * 2], xb = x4[lane * 2 + 1];
            float acc[4];
#pragma unroll
            for (int k = 0; k < 4; ++k) {
                float4 wa = w4[k * (D_DIM / 4) + lane * 2];
                float4 wb = w4[k * (D_DIM / 4) + lane * 2 + 1];
                acc[k] = xa.x * wa.x + xa.y * wa.y + xa.z * wa.z + xa.w * wa.w +
                         xb.x * wb.x + xb.y * wb.y + xb.z * wb.z + xb.w * wb.w;
            }
#pragma unroll
            for (int off = 1; off < 64; off <<= 1) {
#pragma unroll
                for (int k = 0; k < 4; ++k) acc[k] += __shfl_xor(acc[k], off, 64);
            }
            if (lane == 0) {
                float z[4], mx = -1e30f;
#pragma unroll
                for (int k = 0; k < 4; ++k) { z[k] = acc[k] + bsel[k]; mx = fmaxf(mx, z[k]); }
                float e[4], s = 0.0f;
#pragma unroll
                for (int k = 0; k < 4; ++k) { e[k] = fast_exp2((z[k] - mx) * 1.4426950408889634f); s += e[k]; }
                float inv = 1.0f / s;
                float4 o = { e[0] * inv, e[1] * inv, e[2] * inv, e[3] * inv };
                sel_lds[tt] = o;
                ((float4*)SEL)[row] = o;
            }
        }
        __syncthreads();

        const int j = tid;
        float s[16][4];
#pragma unroll
        for (int tt = 0; tt < 16; ++tt) {
            float4 sv = sel_lds[tt];
            s[tt][0] = sv.x; s[tt][1] = sv.y; s[tt][2] = sv.z; s[tt][3] = sv.w;
        }
        float acc[16] = {};
        const float4* M4 = (const float4*)M;
        for (int i = 0; i < H_DIM; ++i) {
            float4 m = M4[i * H_DIM + j];
#pragma unroll
            for (int tt = 0; tt < 16; ++tt) {
                float a = fmaf(m.x, s[tt][0], fmaf(m.y, s[tt][1],
                          fmaf(m.z, s[tt][2], m.w * s[tt][3])));
                a = fabsf(a);
                acc[tt] += fast_exp2(1.2f * fast_log2(a));  // |a|^1.2
            }
        }
#pragma unroll
        for (int tt = 0; tt < 16; ++tt) {
            rN[(size_t)(b * L_DIM + t0 + tt) * H_DIM + j] =
                fast_exp2(-0.8333333333f * fast_log2(acc[tt]));
        }
    } else {
        // ---------- u role: 64x64 f32 GEMM tile ----------
        const int w = bid - 1024;
        const int cb = (w & 3) * GBN;
        const int rb = (w >> 2) * GBM;
        const int tr = tid >> 4, tc = tid & 15;
        const int lrow = tid >> 2;
        const int lcol = (tid & 3) * 8;
        float acc[4][4] = {};
        for (int kt = 0; kt < D_DIM; kt += GBK) {
            float4 xa = *(const float4*)(x + (size_t)(rb + lrow) * D_DIM + kt + lcol);
            float4 xb = *(const float4*)(x + (size_t)(rb + lrow) * D_DIM + kt + lcol + 4);
            float4 wa = *(const float4*)(W_B + (size_t)(cb + lrow) * D_DIM + kt + lcol);
            float4 wb = *(const float4*)(W_B + (size_t)(cb + lrow) * D_DIM + kt + lcol + 4);
            __syncthreads();
            Xs[lcol + 0][lrow] = xa.x; Xs[lcol + 1][lrow] = xa.y;
            Xs[lcol + 2][lrow] = xa.z; Xs[lcol + 3][lrow] = xa.w;
            Xs[lcol + 4][lrow] = xb.x; Xs[lcol + 5][lrow] = xb.y;
            Xs[lcol + 6][lrow] = xb.z; Xs[lcol + 7][lrow] = xb.w;
            Ws[lcol + 0][lrow] = wa.x; Ws[lcol + 1][lrow] = wa.y;
            Ws[lcol + 2][lrow] = wa.z; Ws[lcol + 3][lrow] = wa.w;
            Ws[lcol + 4][lrow] = wb.x; Ws[lcol + 5][lrow] = wb.y;
            Ws[lcol + 6][lrow] = wb.z; Ws[lcol + 7][lrow] = wb.w;
            __syncthreads();
#pragma unroll
            for (int kk = 0; kk < GBK; ++kk) {
                float a0 = Xs[kk][tr * 4 + 0], a1 = Xs[kk][tr * 4 + 1];
                float a2 = Xs[kk][tr * 4 + 2], a3 = Xs[kk][tr * 4 + 3];
                float b0 = Ws[kk][tc * 4 + 0], b1 = Ws[kk][tc * 4 + 1];
                float b2 = Ws[kk][tc * 4 + 2], b3 = Ws[kk][tc * 4 + 3];
                acc[0][0] = fmaf(a0, b0, acc[0][0]); acc[0][1] = fmaf(a0, b1, acc[0][1]);
                acc[0][2] = fmaf(a0, b2, acc[0][2]); acc[0][3] = fmaf(a0, b3, acc[0][3]);
                acc[1][0] = fmaf(a1, b0, acc[1][0]); acc[1][1] = fmaf(a1, b1, acc[1][1]);
                acc[1][2] = fmaf(a1, b2, acc[1][2]); acc[1][3] = fmaf(a1, b3, acc[1][3]);
                acc[2][0] = fmaf(a2, b0, acc[2][0]); acc[2][1] = fmaf(a2, b1, acc[2][1]);
                acc[2][2] = fmaf(a2, b2, acc[2][2]); acc[2][3] = fmaf(a2, b3, acc[2][3]);
                acc[3][0] = fmaf(a3, b0, acc[3][0]); acc[3][1] = fmaf(a3, b1, acc[3][1]);
                acc[3][2] = fmaf(a3, b2, acc[3][2]); acc[3][3] = fmaf(a3, b3, acc[3][3]);
            }
            __syncthreads();
        }
#pragma unroll
        for (int mi = 0; mi < 4; ++mi) {
            float4 v = { acc[mi][0], acc[mi][1], acc[mi][2], acc[mi][3] };
            *(float4*)(out + (size_t)(rb + tr * 4 + mi) * H_DIM + cb + tc * 4) = v;
        }
    }
}

// ---------------- sequential scan (R9 structure + dual-domain sync) ----------------
// 128 wgs: b = wg&15, slice = wg>>4. Under round-robin dispatch all 8 wgs of a
// batch share XCD b%8 -> producer/consumer share an L2. Publish goes to BOTH
// hbL (plain sc0 store, L2-domain) and hb (agent atomic, LLC-domain).
// Consumers poll hbL via sc0 loads (L2-hit latency); per-thread sticky fast_ok
// demotes to the LLC path after 48 failed spins. Either path alone is correct
// (tag+data fused in one 64-bit word; detection==consumption => skew<=1).
// Each wg tag0-inits its OWN rows (both parities, both domains) -- ownership
// partition makes this race-free; replays re-init deterministically.
__global__ __launch_bounds__(256, 1) void k_scan(const float* __restrict__ M,
                                                 const float* __restrict__ SEL,
                                                 const float* __restrict__ rN,
                                                 float* __restrict__ out,
                                                 unsigned long long* hb,
                                                 unsigned long long* hbL) {
    const int wg = blockIdx.x;
    const int b = wg & 15;
    const int slice = wg >> 4;
    const int tid = threadIdx.x;
    const int q = tid >> 6;
    const int ti = tid & 63;
    const int r = ti & 31;
    const int js = ti >> 5;
    const int ig = slice * RPW + r;
    const int jbase = q * 64 + js * 32;

    // tag0-init own rows, both parities, both domains
    if (tid < RPW) {
        const int idx = b * 256 + slice * RPW + tid;
        st_l2(hbL + idx, 0ull);
        st_l2(hbL + 4096 + idx, 0ull);
        __hip_atomic_store(hb + idx, 0ull, __ATOMIC_RELAXED, __HIP_MEMORY_SCOPE_AGENT);
        __hip_atomic_store(hb + 4096 + idx, 0ull, __ATOMIC_RELAXED, __HIP_MEMORY_SCOPE_AGENT);
    }

    float m[128];
    {
        const float4* M4 = (const float4*)M;
#pragma unroll
        for (int jj = 0; jj < 32; ++jj) {
            float4 v = M4[ig * H_DIM + jbase + jj];
            m[jj * 4 + 0] = v.x; m[jj * 4 + 1] = v.y;
            m[jj * 4 + 2] = v.z; m[jj * 4 + 3] = v.w;
        }
    }

    __shared__ float g_lds[256];
    __shared__ float part_lds[2][256];
    bool fast_ok = true;

#pragma unroll 1
    for (int t = 0; t < L_DIM; ++t) {
        // independent loads issued before the poll (latency hidden under it)
        float rn = rN[(size_t)(b * L_DIM + t) * H_DIM + tid];
        float4 s4 = ((const float4*)SEL)[b * L_DIM + t];
        float uval = 0.0f;
        if (tid < RPW) uval = out[(size_t)(b * L_DIM + t) * H_DIM + slice * RPW + tid];

        // dual-domain poll of own tagged word (thread tid <-> column j = tid)
        const size_t off = (size_t)(t & 1) * (16 * 256) + b * 256 + tid;
        const unsigned int tt = (unsigned int)t;
        unsigned long long w = 0;
        bool got = false;
        if (fast_ok) {
#pragma unroll 1
            for (int s = 0; s < 48 && !got; ++s) {
                w = ld_l2(hbL + off);
                got = ((w >> 32) == tt);
            }
            if (!got) fast_ok = false;   // remote placement: demote permanently
        }
        if (!got) {
            do {
                w = __hip_atomic_load(hb + off, __ATOMIC_RELAXED, __HIP_MEMORY_SCOPE_AGENT);
            } while ((w >> 32) != tt);
        }
        float h = __uint_as_float((unsigned int)w);
        g_lds[tid] = h * rn;   // wave-local region; no barrier needed

        float acc0 = 0, acc1 = 0, acc2 = 0, acc3 = 0;
        const float4* g4 = (const float4*)(g_lds + jbase);
#pragma unroll
        for (int jj4 = 0; jj4 < 8; ++jj4) {
            float4 gv = g4[jj4];
            acc0 = fmaf(m[(jj4 * 4 + 0) * 4 + 0], gv.x, acc0);
            acc1 = fmaf(m[(jj4 * 4 + 0) * 4 + 1], gv.x, acc1);
            acc2 = fmaf(m[(jj4 * 4 + 0) * 4 + 2], gv.x, acc2);
            acc3 = fmaf(m[(jj4 * 4 + 0) * 4 + 3], gv.x, acc3);
            acc0 = fmaf(m[(jj4 * 4 + 1) * 4 + 0], gv.y, acc0);
            acc1 = fmaf(m[(jj4 * 4 + 1) * 4 + 1], gv.y, acc1);
            acc2 = fmaf(m[(jj4 * 4 + 1) * 4 + 2], gv.y, acc2);
            acc3 = fmaf(m[(jj4 * 4 + 1) * 4 + 3], gv.y, acc3);
            acc0 = fmaf(m[(jj4 * 4 + 2) * 4 + 0], gv.z, acc0);
            acc1 = fmaf(m[(jj4 * 4 + 2) * 4 + 1], gv.z, acc1);
            acc2 = fmaf(m[(jj4 * 4 + 2) * 4 + 2], gv.z, acc2);
            acc3 = fmaf(m[(jj4 * 4 + 2) * 4 + 3], gv.z, acc3);
            acc0 = fmaf(m[(jj4 * 4 + 3) * 4 + 0], gv.w, acc0);
            acc1 = fmaf(m[(jj4 * 4 + 3) * 4 + 1], gv.w, acc1);
            acc2 = fmaf(m[(jj4 * 4 + 3) * 4 + 2], gv.w, acc2);
            acc3 = fmaf(m[(jj4 * 4 + 3) * 4 + 3], gv.w, acc3);
        }
        float part = fmaf(acc0, s4.x, fmaf(acc1, s4.y, fmaf(acc2, s4.z, acc3 * s4.w)));
        part_lds[t & 1][tid] = part;
        __syncthreads();

        if (tid < RPW) {
            float hn = uval;
#pragma unroll
            for (int p = 0; p < 8; ++p) hn += part_lds[t & 1][tid + 32 * p];
            unsigned long long pw = ((unsigned long long)(tt + 1) << 32) |
                                    (unsigned long long)__float_as_uint(hn);
            const size_t nxt = (size_t)((t + 1) & 1) * (16 * 256) + b * 256 + slice * RPW + tid;
            st_l2(hbL + nxt, pw);                       // L2-domain (fast, same-XCD)
            __hip_atomic_store(hb + nxt, pw,            // LLC-domain (always correct)
                               __ATOMIC_RELAXED, __HIP_MEMORY_SCOPE_AGENT);
            out[(size_t)(b * L_DIM + t) * H_DIM + slice * RPW + tid] = hn;
        }
    }
}

extern "C" void kernel_launch(void* const* d_in, const int* in_sizes, int n_in,
                              void* d_out, int out_size, void* d_ws, size_t ws_size,
                              hipStream_t stream) {
    const float* x    = (const float*)d_in[0];  // (16,1024,512)
    const float* Wsel = (const float*)d_in[1];  // (4,512)
    const float* bsel = (const float*)d_in[2];  // (4,)
    const float* W_B  = (const float*)d_in[3];  // (256,512)
    const float* M    = (const float*)d_in[4];  // (256,256,4)
    float* out = (float*)d_out;                 // (16,1024,256)

    char* ws = (char*)d_ws;
    unsigned long long* hb  = (unsigned long long*)(ws + OFF_HB);
    unsigned long long* hbL = (unsigned long long*)(ws + OFF_HBL);
    float* SEL = (float*)(ws + OFF_SEL);
    float* rN  = (float*)(ws + OFF_RN);

    k_par<<<2048, 256, 0, stream>>>(x, Wsel, bsel, W_B, M, SEL, rN, out);
    k_scan<<<B_DIM * SLICES, 256, 0, stream>>>(M, SEL, rN, out, hb, hbL);
}

// Round 13
// 1301.289 us; speedup vs baseline: 1.6465x; 1.0128x over previous
//
#include <hip/hip_runtime.h>

#define B_DIM 16
#define L_DIM 1024
#define D_DIM 512
#define H_DIM 256
#define K_DIM 4

#define SLICES 8        // wgs per batch
#define RPW 32          // rows per wg (H_DIM / SLICES)

// ---------------- workspace layout (bytes) ----------------
#define OFF_HB  0                      // u64 hb[2][16][256] (tag<<32 | f32 bits), 64KB
#define OFF_SEL 65536                  // float SEL[16384*4]
#define OFF_RN  327680                 // float rN[16384*256]

__device__ __forceinline__ float fast_log2(float x) { return __builtin_amdgcn_logf(x); }
__device__ __forceinline__ float fast_exp2(float x) { return __builtin_amdgcn_exp2f(x); }

// ---------------- fused parallel phase (R9-proven) ----------------
#define GBM 64
#define GBN 64
#define GBK 32
__global__ __launch_bounds__(256) void k_par(const float* __restrict__ x,
                                             const float* __restrict__ Wsel,
                                             const float* __restrict__ bsel,
                                             const float* __restrict__ W_B,
                                             const float* __restrict__ M,
                                             float* __restrict__ SEL,
                                             float* __restrict__ rN,
                                             float* __restrict__ out,
                                             unsigned long long* __restrict__ hb) {
    __shared__ float Xs[GBK][GBM + 1];
    __shared__ float Ws[GBK][GBN + 1];
    __shared__ float4 sel_lds[16];
    const int bid = blockIdx.x;
    const int tid = threadIdx.x;

    if (bid >= 2048) {
        for (int i = tid; i < 2 * 16 * 256; i += 256) hb[i] = 0ull;
        return;
    }

    if (bid < 1024) {
        // ---------- norm role ----------
        const int b = bid >> 6;
        const int t0 = (bid & 63) << 4;
        const int lane = tid & 63;
        const int wv = tid >> 6;
        const float4* w4 = (const float4*)Wsel;
#pragma unroll
        for (int rr = 0; rr < 4; ++rr) {
            const int tt = wv * 4 + rr;
            const int row = b * L_DIM + t0 + tt;
            const float4* x4 = (const float4*)(x + (size_t)row * D_DIM);
            float4 xa = x4[lane * 2], xb = x4[lane * 2 + 1];
            float acc[4];
#pragma unroll
            for (int k = 0; k < 4; ++k) {
                float4 wa = w4[k * (D_DIM / 4) + lane * 2];
                float4 wb = w4[k * (D_DIM / 4) + lane * 2 + 1];
                acc[k] = xa.x * wa.x + xa.y * wa.y + xa.z * wa.z + xa.w * wa.w +
                         xb.x * wb.x + xb.y * wb.y + xb.z * wb.z + xb.w * wb.w;
            }
#pragma unroll
            for (int off = 1; off < 64; off <<= 1) {
#pragma unroll
                for (int k = 0; k < 4; ++k) acc[k] += __shfl_xor(acc[k], off, 64);
            }
            if (lane == 0) {
                float z[4], mx = -1e30f;
#pragma unroll
                for (int k = 0; k < 4; ++k) { z[k] = acc[k] + bsel[k]; mx = fmaxf(mx, z[k]); }
                float e[4], s = 0.0f;
#pragma unroll
                for (int k = 0; k < 4; ++k) { e[k] = fast_exp2((z[k] - mx) * 1.4426950408889634f); s += e[k]; }
                float inv = 1.0f / s;
                float4 o = { e[0] * inv, e[1] * inv, e[2] * inv, e[3] * inv };
                sel_lds[tt] = o;
                ((float4*)SEL)[row] = o;
            }
        }
        __syncthreads();

        const int j = tid;
        float s[16][4];
#pragma unroll
        for (int tt = 0; tt < 16; ++tt) {
            float4 sv = sel_lds[tt];
            s[tt][0] = sv.x; s[tt][1] = sv.y; s[tt][2] = sv.z; s[tt][3] = sv.w;
        }
        float acc[16] = {};
        const float4* M4 = (const float4*)M;
        for (int i = 0; i < H_DIM; ++i) {
            float4 m = M4[i * H_DIM + j];
#pragma unroll
            for (int tt = 0; tt < 16; ++tt) {
                float a = fmaf(m.x, s[tt][0], fmaf(m.y, s[tt][1],
                          fmaf(m.z, s[tt][2], m.w * s[tt][3])));
                a = fabsf(a);
                acc[tt] += fast_exp2(1.2f * fast_log2(a));  // |a|^1.2
            }
        }
#pragma unroll
        for (int tt = 0; tt < 16; ++tt) {
            rN[(size_t)(b * L_DIM + t0 + tt) * H_DIM + j] =
                fast_exp2(-0.8333333333f * fast_log2(acc[tt]));
        }
    } else {
        // ---------- u role: 64x64 f32 GEMM tile ----------
        const int w = bid - 1024;
        const int cb = (w & 3) * GBN;
        const int rb = (w >> 2) * GBM;
        const int tr = tid >> 4, tc = tid & 15;
        const int lrow = tid >> 2;
        const int lcol = (tid & 3) * 8;
        float acc[4][4] = {};
        for (int kt = 0; kt < D_DIM; kt += GBK) {
            float4 xa = *(const float4*)(x + (size_t)(rb + lrow) * D_DIM + kt + lcol);
            float4 xb = *(const float4*)(x + (size_t)(rb + lrow) * D_DIM + kt + lcol + 4);
            float4 wa = *(const float4*)(W_B + (size_t)(cb + lrow) * D_DIM + kt + lcol);
            float4 wb = *(const float4*)(W_B + (size_t)(cb + lrow) * D_DIM + kt + lcol + 4);
            __syncthreads();
            Xs[lcol + 0][lrow] = xa.x; Xs[lcol + 1][lrow] = xa.y;
            Xs[lcol + 2][lrow] = xa.z; Xs[lcol + 3][lrow] = xa.w;
            Xs[lcol + 4][lrow] = xb.x; Xs[lcol + 5][lrow] = xb.y;
            Xs[lcol + 6][lrow] = xb.z; Xs[lcol + 7][lrow] = xb.w;
            Ws[lcol + 0][lrow] = wa.x; Ws[lcol + 1][lrow] = wa.y;
            Ws[lcol + 2][lrow] = wa.z; Ws[lcol + 3][lrow] = wa.w;
            Ws[lcol + 4][lrow] = wb.x; Ws[lcol + 5][lrow] = wb.y;
            Ws[lcol + 6][lrow] = wb.z; Ws[lcol + 7][lrow] = wb.w;
            __syncthreads();
#pragma unroll
            for (int kk = 0; kk < GBK; ++kk) {
                float a0 = Xs[kk][tr * 4 + 0], a1 = Xs[kk][tr * 4 + 1];
                float a2 = Xs[kk][tr * 4 + 2], a3 = Xs[kk][tr * 4 + 3];
                float b0 = Ws[kk][tc * 4 + 0], b1 = Ws[kk][tc * 4 + 1];
                float b2 = Ws[kk][tc * 4 + 2], b3 = Ws[kk][tc * 4 + 3];
                acc[0][0] = fmaf(a0, b0, acc[0][0]); acc[0][1] = fmaf(a0, b1, acc[0][1]);
                acc[0][2] = fmaf(a0, b2, acc[0][2]); acc[0][3] = fmaf(a0, b3, acc[0][3]);
                acc[1][0] = fmaf(a1, b0, acc[1][0]); acc[1][1] = fmaf(a1, b1, acc[1][1]);
                acc[1][2] = fmaf(a1, b2, acc[1][2]); acc[1][3] = fmaf(a1, b3, acc[1][3]);
                acc[2][0] = fmaf(a2, b0, acc[2][0]); acc[2][1] = fmaf(a2, b1, acc[2][1]);
                acc[2][2] = fmaf(a2, b2, acc[2][2]); acc[2][3] = fmaf(a2, b3, acc[2][3]);
                acc[3][0] = fmaf(a3, b0, acc[3][0]); acc[3][1] = fmaf(a3, b1, acc[3][1]);
                acc[3][2] = fmaf(a3, b2, acc[3][2]); acc[3][3] = fmaf(a3, b3, acc[3][3]);
            }
            __syncthreads();
        }
#pragma unroll
        for (int mi = 0; mi < 4; ++mi) {
            float4 v = { acc[mi][0], acc[mi][1], acc[mi][2], acc[mi][3] };
            *(float4*)(out + (size_t)(rb + tr * 4 + mi) * H_DIM + cb + tc * 4) = v;
        }
    }
}

// ---------------- sequential scan (R9 structure + staggered double poll) ----------------
// 128 wgs: b = wg&15, slice = wg>>4. Tagged 64-bit words: poll IS the data load.
// Wave q writes AND reads only g_lds[q*64 .. q*64+64) -> no barrier before the
// FMA loop. part_lds parity-double-buffered -> one barrier/step. Wave 0
// publishes all 32 rows as one contiguous burst. Poll issues TWO independent
// loads staggered ~128cy apart (s_sleep(2) between issues) -> detect
// quantization halves vs a single dependent-load spin.
__global__ __launch_bounds__(256, 1) void k_scan(const float* __restrict__ M,
                                                 const float* __restrict__ SEL,
                                                 const float* __restrict__ rN,
                                                 float* __restrict__ out,
                                                 unsigned long long* hb) {
    const int wg = blockIdx.x;
    const int b = wg & 15;
    const int slice = wg >> 4;
    const int tid = threadIdx.x;
    const int q = tid >> 6;
    const int ti = tid & 63;
    const int r = ti & 31;
    const int js = ti >> 5;
    const int ig = slice * RPW + r;
    const int jbase = q * 64 + js * 32;

    float m[128];
    {
        const float4* M4 = (const float4*)M;
#pragma unroll
        for (int jj = 0; jj < 32; ++jj) {
            float4 v = M4[ig * H_DIM + jbase + jj];
            m[jj * 4 + 0] = v.x; m[jj * 4 + 1] = v.y;
            m[jj * 4 + 2] = v.z; m[jj * 4 + 3] = v.w;
        }
    }

    __shared__ float g_lds[256];
    __shared__ float part_lds[2][256];

#pragma unroll 1
    for (int t = 0; t < L_DIM; ++t) {
        // independent loads issued before the poll (latency hidden under it)
        float rn = rN[(size_t)(b * L_DIM + t) * H_DIM + tid];
        float4 s4 = ((const float4*)SEL)[b * L_DIM + t];
        float uval = 0.0f;
        if (tid < RPW) uval = out[(size_t)(b * L_DIM + t) * H_DIM + slice * RPW + tid];

        // staggered double poll of own tagged word (thread tid <-> column j = tid)
        unsigned long long* src = hb + (size_t)(t & 1) * (16 * 256) + b * 256 + tid;
        const unsigned int tt = (unsigned int)t;
        unsigned long long w = __hip_atomic_load(src, __ATOMIC_RELAXED, __HIP_MEMORY_SCOPE_AGENT);
        if ((w >> 32) != tt) {
            unsigned long long wa, wb;
            do {
                wa = __hip_atomic_load(src, __ATOMIC_RELAXED, __HIP_MEMORY_SCOPE_AGENT);
                __builtin_amdgcn_s_sleep(2);   // stagger second issue ~128cy
                wb = __hip_atomic_load(src, __ATOMIC_RELAXED, __HIP_MEMORY_SCOPE_AGENT);
                w = ((wa >> 32) == tt) ? wa : wb;
            } while ((w >> 32) != tt);
        }
        float h = __uint_as_float((unsigned int)w);
        g_lds[tid] = h * rn;   // wave-local region; no barrier needed

        float acc0 = 0, acc1 = 0, acc2 = 0, acc3 = 0;
        const float4* g4 = (const float4*)(g_lds + jbase);
#pragma unroll
        for (int jj4 = 0; jj4 < 8; ++jj4) {
            float4 gv = g4[jj4];
            acc0 = fmaf(m[(jj4 * 4 + 0) * 4 + 0], gv.x, acc0);
            acc1 = fmaf(m[(jj4 * 4 + 0) * 4 + 1], gv.x, acc1);
            acc2 = fmaf(m[(jj4 * 4 + 0) * 4 + 2], gv.x, acc2);
            acc3 = fmaf(m[(jj4 * 4 + 0) * 4 + 3], gv.x, acc3);
            acc0 = fmaf(m[(jj4 * 4 + 1) * 4 + 0], gv.y, acc0);
            acc1 = fmaf(m[(jj4 * 4 + 1) * 4 + 1], gv.y, acc1);
            acc2 = fmaf(m[(jj4 * 4 + 1) * 4 + 2], gv.y, acc2);
            acc3 = fmaf(m[(jj4 * 4 + 1) * 4 + 3], gv.y, acc3);
            acc0 = fmaf(m[(jj4 * 4 + 2) * 4 + 0], gv.z, acc0);
            acc1 = fmaf(m[(jj4 * 4 + 2) * 4 + 1], gv.z, acc1);
            acc2 = fmaf(m[(jj4 * 4 + 2) * 4 + 2], gv.z, acc2);
            acc3 = fmaf(m[(jj4 * 4 + 2) * 4 + 3], gv.z, acc3);
            acc0 = fmaf(m[(jj4 * 4 + 3) * 4 + 0], gv.w, acc0);
            acc1 = fmaf(m[(jj4 * 4 + 3) * 4 + 1], gv.w, acc1);
            acc2 = fmaf(m[(jj4 * 4 + 3) * 4 + 2], gv.w, acc2);
            acc3 = fmaf(m[(jj4 * 4 + 3) * 4 + 3], gv.w, acc3);
        }
        float part = fmaf(acc0, s4.x, fmaf(acc1, s4.y, fmaf(acc2, s4.z, acc3 * s4.w)));
        part_lds[t & 1][tid] = part;
        __syncthreads();

        if (tid < RPW) {
            float hn = uval;
#pragma unroll
            for (int p = 0; p < 8; ++p) hn += part_lds[t & 1][tid + 32 * p];
            unsigned long long pw = ((unsigned long long)(tt + 1) << 32) |
                                    (unsigned long long)__float_as_uint(hn);
            __hip_atomic_store(hb + (size_t)((t + 1) & 1) * (16 * 256) + b * 256 + slice * RPW + tid,
                               pw, __ATOMIC_RELAXED, __HIP_MEMORY_SCOPE_AGENT);
            out[(size_t)(b * L_DIM + t) * H_DIM + slice * RPW + tid] = hn;
        }
    }
}

extern "C" void kernel_launch(void* const* d_in, const int* in_sizes, int n_in,
                              void* d_out, int out_size, void* d_ws, size_t ws_size,
                              hipStream_t stream) {
    const float* x    = (const float*)d_in[0];  // (16,1024,512)
    const float* Wsel = (const float*)d_in[1];  // (4,512)
    const float* bsel = (const float*)d_in[2];  // (4,)
    const float* W_B  = (const float*)d_in[3];  // (256,512)
    const float* M    = (const float*)d_in[4];  // (256,256,4)
    float* out = (float*)d_out;                 // (16,1024,256)

    char* ws = (char*)d_ws;
    unsigned long long* hb = (unsigned long long*)(ws + OFF_HB);
    float* SEL = (float*)(ws + OFF_SEL);
    float* rN  = (float*)(ws + OFF_RN);

    k_par<<<2049, 256, 0, stream>>>(x, Wsel, bsel, W_B, M, SEL, rN, out, hb);
    k_scan<<<B_DIM * SLICES, 256, 0, stream>>>(M, SEL, rN, out, hb);
}